// Round 9
// baseline (591.451 us; speedup 1.0000x reference)
//
#include <hip/hip_runtime.h>

// Problem constants (reference file)
#define GG 8
#define MPG 2048
#define KD 4096
#define ND 4096

using i32x4 = __attribute__((ext_vector_type(4))) int;

__device__ __forceinline__ int pack4(i32x4 v) {
  return (int)((unsigned)(v[0] & 0xff) | ((unsigned)(v[1] & 0xff) << 8) |
               ((unsigned)(v[2] & 0xff) << 16) | ((unsigned)(v[3] & 0xff) << 24));
}

__device__ __forceinline__ void pack16(const int* __restrict__ src, char* __restrict__ dst, long e) {
  i32x4 x0 = *(const i32x4*)(src + e);
  i32x4 x1 = *(const i32x4*)(src + e + 4);
  i32x4 x2 = *(const i32x4*)(src + e + 8);
  i32x4 x3 = *(const i32x4*)(src + e + 12);
  i32x4 p;
  p[0] = pack4(x0); p[1] = pack4(x1); p[2] = pack4(x2); p[3] = pack4(x3);
  *(i32x4*)(dst + e) = p;
}

// int32 -> int8 pack (standalone, prologue / fallback)
__global__ void conv_kernel(const int* __restrict__ src, char* __restrict__ dst, long nelem) {
  long t = (long)blockIdx.x * blockDim.x + threadIdx.x;
  long stride = (long)gridDim.x * blockDim.x * 16;
  for (long e = t * 16; e < nelem; e += stride) pack16(src, dst, e);
}

__device__ __forceinline__ void gload_lds16(const void* g, void* l) {
  __builtin_amdgcn_global_load_lds(
      (const __attribute__((address_space(1))) unsigned int*)g,
      (__attribute__((address_space(3))) unsigned int*)l, 16, 0, 0);
}

#define CFENCE() asm volatile("" ::: "memory")

// ---------------------------------------------------------------------------
// Fused per-group kernel:
//   blocks [0,256):    GEMM of group g — 256x128 tile, BK=128 B, 4 waves
//                      (2Mx2N, wave=128x64), single 48 KiB LDS buffer,
//                      T1/T2 swizzles, setprio (round-7 structure, proven).
//   blocks [256,512):  int32->int8 conv of group g+1's A and B slabs
//                      (pure HBM stream — overlaps the GEMM's MFMA/LDS time).
// Race ledger: reads int8 slabs g (written by previous launch, stream order);
// writes int8 slabs g+1 (disjoint). Deterministic.
// ---------------------------------------------------------------------------
constexpr int NTK = KD / 128;   // 32 K-tiles
constexpr int NCONV = 256;

__global__ __launch_bounds__(256, 2) void fused_i8(
    const char* __restrict__ Ag8,    // wsA + g*aSlab  (int8, this group's A)
    const char* __restrict__ Bg8,    // wsB + g*bSlab  (int8, this group's B)
    const float* __restrict__ ls,
    const float* __restrict__ rs,
    float* __restrict__ out,
    int g,
    const int* __restrict__ A32,     // full int32 inputs (conv source)
    const int* __restrict__ B32,
    char* __restrict__ wsA,          // full int8 workspaces (conv dest)
    char* __restrict__ wsB,
    int gnext)                       // group to convert (>=GG -> no conv work)
{
  extern __shared__ char lds[];   // 49152 B: [ A 32KB | B 16KB ] (gemm only)
  const int tid = threadIdx.x;

  if (blockIdx.x >= 256) {
    // ---------------- conv path ----------------
    if (gnext < GG) {
      const long aSlab = (long)MPG * KD;
      const long bSlab = (long)ND * KD;
      const long t = (long)(blockIdx.x - 256) * 256 + tid;
      const long stride = (long)NCONV * 256 * 16;
      const int* srcA = A32 + (size_t)gnext * aSlab;
      char* dstA = wsA + (size_t)gnext * aSlab;
      for (long e = t * 16; e < aSlab; e += stride) pack16(srcA, dstA, e);
      const int* srcB = B32 + (size_t)gnext * bSlab;
      char* dstB = wsB + (size_t)gnext * bSlab;
      for (long e = t * 16; e < bSlab; e += stride) pack16(srcB, dstB, e);
    }
    return;
  }

  // ---------------- gemm path (round-7 body, verbatim) ----------------
  const int lane = tid & 63;
  const int wave = tid >> 6;      // 0..3

  // bijective XCD-aware swizzle over nwg=256 (q=32)
  const int bid = blockIdx.x;
  const int wg = (bid & 7) * 32 + (bid >> 3);
  const int bm = (wg >> 5) * 256;      // 8 m-tiles
  const int bn = (wg & 31) * 128;      // 32 n-tiles

  // staging: thread t covers LDS-linear off = i*4096 + t*16
  // row = i*32 + (t>>3), linear col = (t&7)*16; global col pre-inverse-swizzled
  const int srow = tid >> 3;                                  // 0..31
  const int scol = ((tid & 7) << 4) ^ ((srow & 7) << 4);
  const char* Ag = Ag8 + (size_t)bm * KD;
  const char* Bg = Bg8 + (size_t)bn * KD;
  const int voff = srow * KD + scol;
  char* wbase = lds + wave * 1024;     // wave-uniform; HW adds lane*16

  auto stage = [&](int kt) {
    const int ko = kt << 7;
#pragma unroll
    for (int i = 0; i < 8; ++i)   // A: 256 rows x 128 B
      gload_lds16(Ag + (size_t)(ko + voff) + (size_t)i * (32 * KD), wbase + i * 4096);
#pragma unroll
    for (int i = 0; i < 4; ++i)   // B: 128 rows x 128 B
      gload_lds16(Bg + (size_t)(ko + voff) + (size_t)i * (32 * KD), wbase + 32768 + i * 4096);
  };

  const int wm = wave >> 1;            // 0..1  (M half: 128 rows)
  const int wn = wave & 1;             // 0..1  (N half: 64 cols)
  const int r16 = lane & 15;
  const int klane = (lane >> 4) << 4;          // 0,16,32,48
  const int sx = (r16 & 7) << 4;               // swizzle XOR (row&7 == r16&7)
  const char* pA = lds + (size_t)(wm * 128 + r16) * 128;
  const char* pB = lds + 32768 + (size_t)(wn * 64 + r16) * 128;
  const int kx0 = klane ^ sx;
  const int kx1 = (64 + klane) ^ sx;

  i32x4 acc[8][4] = {};

  stage(0);
  asm volatile("s_waitcnt vmcnt(0)" ::: "memory");
  __builtin_amdgcn_s_barrier();
  CFENCE();

#pragma unroll 1
  for (int kt = 0; kt < NTK; ++kt) {
    i32x4 bf0[4], bf1[4], af0[4], af1[4];
#pragma unroll
    for (int n = 0; n < 4; ++n) bf0[n] = *(const i32x4*)(pB + n * 2048 + kx0);
#pragma unroll
    for (int m = 0; m < 4; ++m) af0[m] = *(const i32x4*)(pA + m * 2048 + kx0);
#pragma unroll
    for (int m = 0; m < 4; ++m) af1[m] = *(const i32x4*)(pA + (4 + m) * 2048 + kx0);
    __builtin_amdgcn_s_setprio(1);
#pragma unroll
    for (int m = 0; m < 4; ++m)
#pragma unroll
      for (int n = 0; n < 4; ++n)
        acc[m][n] = __builtin_amdgcn_mfma_i32_16x16x64_i8(af0[m], bf0[n], acc[m][n], 0, 0, 0);
    __builtin_amdgcn_s_setprio(0);
#pragma unroll
    for (int n = 0; n < 4; ++n) bf1[n] = *(const i32x4*)(pB + n * 2048 + kx1);
#pragma unroll
    for (int m = 0; m < 4; ++m) af0[m] = *(const i32x4*)(pA + m * 2048 + kx1);
    __builtin_amdgcn_s_setprio(1);
#pragma unroll
    for (int m = 0; m < 4; ++m)
#pragma unroll
      for (int n = 0; n < 4; ++n)
        acc[4 + m][n] = __builtin_amdgcn_mfma_i32_16x16x64_i8(af1[m], bf0[n], acc[4 + m][n], 0, 0, 0);
    __builtin_amdgcn_s_setprio(0);
#pragma unroll
    for (int m = 0; m < 4; ++m) af1[m] = *(const i32x4*)(pA + (4 + m) * 2048 + kx1);
    __builtin_amdgcn_s_setprio(1);
#pragma unroll
    for (int m = 0; m < 4; ++m)
#pragma unroll
      for (int n = 0; n < 4; ++n)
        acc[m][n] = __builtin_amdgcn_mfma_i32_16x16x64_i8(af0[m], bf1[n], acc[m][n], 0, 0, 0);
#pragma unroll
    for (int m = 0; m < 4; ++m)
#pragma unroll
      for (int n = 0; n < 4; ++n)
        acc[4 + m][n] = __builtin_amdgcn_mfma_i32_16x16x64_i8(af1[m], bf1[n], acc[4 + m][n], 0, 0, 0);
    __builtin_amdgcn_s_setprio(0);

    asm volatile("s_waitcnt lgkmcnt(0)" ::: "memory");
    __builtin_amdgcn_sched_barrier(0);
    __builtin_amdgcn_s_barrier();
    CFENCE();
    if (kt + 1 < NTK) stage(kt + 1);
    asm volatile("s_waitcnt vmcnt(0)" ::: "memory");
    __builtin_amdgcn_s_barrier();
    CFENCE();
  }

  // epilogue: C/D layout col=lane&15, row=(lane>>4)*4+reg
  const size_t orow0 = (size_t)g * MPG + bm + wm * 128 + ((lane >> 4) << 2);
  const int col0 = bn + wn * 64 + r16;
  float rsv[4];
#pragma unroll
  for (int n = 0; n < 4; ++n) rsv[n] = rs[(size_t)g * ND + col0 + n * 16];
#pragma unroll
  for (int m = 0; m < 8; ++m) {
#pragma unroll
    for (int q = 0; q < 4; ++q) {
      size_t row = orow0 + m * 16 + q;
      float lsv = ls[row];
#pragma unroll
      for (int n = 0; n < 4; ++n)
        out[row * ND + col0 + n * 16] = (float)acc[m][n][q] * lsv * rsv[n];
    }
  }
}

// ---------------------------------------------------------------------------
// Fallback 128x128 kernel (round-1, known-good) for ws/attr contingencies.
// ---------------------------------------------------------------------------
constexpr int BM = 128, BN = 128, BK = 64;

template<bool DIRECT>
__global__ __launch_bounds__(256) void gemm_i8(
    const void* __restrict__ Aptr, const void* __restrict__ Bptr,
    const float* __restrict__ ls, const float* __restrict__ rs,
    float* __restrict__ out, int g0)
{
  __shared__ char lA[BM * BK];
  __shared__ char lB[BN * BK];

  const int gl = blockIdx.z;
  const int g = g0 + gl;
  const int bm = blockIdx.y * BM;
  const int bn = blockIdx.x * BN;
  const int tid = threadIdx.x;
  const int lane = tid & 63;
  const int wave = tid >> 6;
  const int wr = (wave >> 1) * 64;
  const int wc = (wave & 1) * 64;
  const int r16 = lane & 15;
  const int kb = (lane >> 4) * 16;

  i32x4 acc[4][4] = {};

  if constexpr (!DIRECT) {
    const char* Ag = (const char*)Aptr + ((size_t)gl * MPG + bm) * KD;
    const char* Bg = (const char*)Bptr + ((size_t)gl * ND + bn) * KD;
    const int srow = tid >> 2;
    const int skoff = (tid & 3) * 16;
    const char* pa0 = Ag + (size_t)srow * KD + skoff;
    const char* pa1 = Ag + (size_t)(srow + 64) * KD + skoff;
    const char* pb0 = Bg + (size_t)srow * KD + skoff;
    const char* pb1 = Bg + (size_t)(srow + 64) * KD + skoff;
    char* la0 = lA + wave * 1024;
    char* la1 = lA + 4096 + wave * 1024;
    char* lb0 = lB + wave * 1024;
    char* lb1 = lB + 4096 + wave * 1024;

    for (int k0 = 0; k0 < KD; k0 += BK) {
      gload_lds16(pa0 + k0, la0);
      gload_lds16(pa1 + k0, la1);
      gload_lds16(pb0 + k0, lb0);
      gload_lds16(pb1 + k0, lb1);
      __syncthreads();
      i32x4 af[4], bf[4];
#pragma unroll
      for (int m = 0; m < 4; ++m) af[m] = *(const i32x4*)(lA + (wr + m * 16 + r16) * BK + kb);
#pragma unroll
      for (int n = 0; n < 4; ++n) bf[n] = *(const i32x4*)(lB + (wc + n * 16 + r16) * BK + kb);
#pragma unroll
      for (int m = 0; m < 4; ++m)
#pragma unroll
        for (int n = 0; n < 4; ++n)
          acc[m][n] = __builtin_amdgcn_mfma_i32_16x16x64_i8(af[m], bf[n], acc[m][n], 0, 0, 0);
      __syncthreads();
    }
  } else {
    const int* Ag = (const int*)Aptr + ((size_t)gl * MPG + bm) * KD;
    const int* Bg = (const int*)Bptr + ((size_t)gl * ND + bn) * KD;
    const int drow = tid >> 1;
    const int dk = (tid & 1) * 32;

    for (int k0 = 0; k0 < KD; k0 += BK) {
      int pa[8], pb[8];
#pragma unroll
      for (int j = 0; j < 8; ++j) pa[j] = pack4(*(const i32x4*)(Ag + (size_t)drow * KD + k0 + dk + j * 4));
#pragma unroll
      for (int j = 0; j < 8; ++j) pb[j] = pack4(*(const i32x4*)(Bg + (size_t)drow * KD + k0 + dk + j * 4));
      __syncthreads();
      *(i32x4*)(lA + drow * 64 + dk)      = *(i32x4*)(pa);
      *(i32x4*)(lA + drow * 64 + dk + 16) = *(i32x4*)(pa + 4);
      *(i32x4*)(lB + drow * 64 + dk)      = *(i32x4*)(pb);
      *(i32x4*)(lB + drow * 64 + dk + 16) = *(i32x4*)(pb + 4);
      __syncthreads();
      i32x4 af[4], bf[4];
#pragma unroll
      for (int m = 0; m < 4; ++m) af[m] = *(const i32x4*)(lA + (wr + m * 16 + r16) * BK + kb);
#pragma unroll
      for (int n = 0; n < 4; ++n) bf[n] = *(const i32x4*)(lB + (wc + n * 16 + r16) * BK + kb);
#pragma unroll
      for (int m = 0; m < 4; ++m)
#pragma unroll
        for (int n = 0; n < 4; ++n)
          acc[m][n] = __builtin_amdgcn_mfma_i32_16x16x64_i8(af[m], bf[n], acc[m][n], 0, 0, 0);
    }
  }

  const size_t trow0 = (size_t)g * MPG + bm + wr + (lane >> 4) * 4;
  const int col0 = bn + wc + r16;
  float rsv[4];
#pragma unroll
  for (int n = 0; n < 4; ++n) rsv[n] = rs[(size_t)g * ND + col0 + n * 16];
#pragma unroll
  for (int m = 0; m < 4; ++m) {
#pragma unroll
    for (int q = 0; q < 4; ++q) {
      size_t row = trow0 + m * 16 + q;
      float lsv = ls[row];
#pragma unroll
      for (int n = 0; n < 4; ++n)
        out[row * ND + col0 + n * 16] = (float)acc[m][n][q] * lsv * rsv[n];
    }
  }
}

extern "C" void kernel_launch(void* const* d_in, const int* in_sizes, int n_in,
                              void* d_out, int out_size, void* d_ws, size_t ws_size,
                              hipStream_t stream) {
  const int* A32 = (const int*)d_in[0];
  const int* B32 = (const int*)d_in[1];
  const float* ls = (const float*)d_in[2];
  const float* rs = (const float*)d_in[3];
  float* out = (float*)d_out;

  const size_t aE = (size_t)GG * MPG * KD;
  const size_t bE = (size_t)GG * ND * KD;
  const size_t aSlab = (size_t)MPG * KD;
  const size_t bSlab = (size_t)ND * KD;

  const int smem = 49152;   // A 32 KiB + B 16 KiB, single buffer
  bool big_lds_ok =
      hipFuncSetAttribute((const void*)fused_i8,
                          hipFuncAttributeMaxDynamicSharedMemorySize, smem) == hipSuccess;

  if (d_ws && ws_size >= aE + bE && big_lds_ok) {
    char* wsA = (char*)d_ws;
    char* wsB = wsA + aE;
    // prologue: convert group 0 only
    conv_kernel<<<1024, 256, 0, stream>>>(A32, wsA, (long)aSlab);
    conv_kernel<<<2048, 256, 0, stream>>>(B32, wsB, (long)bSlab);
    // pipelined: launch g = GEMM(g) [256 blocks] + conv(g+1) [256 blocks]
    for (int g = 0; g < GG; ++g) {
      fused_i8<<<256 + NCONV, 256, smem, stream>>>(
          wsA + (size_t)g * aSlab, wsB + (size_t)g * bSlab,
          ls, rs, out, g,
          A32, B32, wsA, wsB, g + 1);
    }
  } else if (d_ws && ws_size >= aE + bE) {
    char* wsA = (char*)d_ws;
    char* wsB = wsA + aE;
    conv_kernel<<<8192, 256, 0, stream>>>(A32, wsA, (long)aE);
    conv_kernel<<<16384, 256, 0, stream>>>(B32, wsB, (long)bE);
    dim3 grid(ND / BN, MPG / BM, GG);
    gemm_i8<false><<<grid, dim3(256), 0, stream>>>(wsA, wsB, ls, rs, out, 0);
  } else if (d_ws && ws_size >= aSlab + bSlab) {
    char* wsA = (char*)d_ws;
    char* wsB = wsA + aSlab;
    for (int gidx = 0; gidx < GG; ++gidx) {
      conv_kernel<<<2048, 256, 0, stream>>>(A32 + (size_t)gidx * aSlab, wsA, (long)aSlab);
      conv_kernel<<<4096, 256, 0, stream>>>(B32 + (size_t)gidx * bSlab, wsB, (long)bSlab);
      dim3 grid(ND / BN, MPG / BM, 1);
      gemm_i8<false><<<grid, dim3(256), 0, stream>>>(wsA, wsB, ls, rs, out, gidx);
    }
  } else {
    dim3 grid(ND / BN, MPG / BM, GG);
    gemm_i8<true><<<grid, dim3(256), 0, stream>>>(A32, B32, ls, rs, out, 0);
  }
}

// Round 10
// 487.646 us; speedup vs baseline: 1.2129x; 1.2129x over previous
//
#include <hip/hip_runtime.h>

// Problem constants (reference file)
#define GG 8
#define MPG 2048
#define KD 4096
#define ND 4096

using i32x4 = __attribute__((ext_vector_type(4))) int;

__device__ __forceinline__ int pack4(i32x4 v) {
  return (int)((unsigned)(v[0] & 0xff) | ((unsigned)(v[1] & 0xff) << 8) |
               ((unsigned)(v[2] & 0xff) << 16) | ((unsigned)(v[3] & 0xff) << 24));
}

__device__ __forceinline__ void pack16(const int* __restrict__ src, char* __restrict__ dst, long e) {
  i32x4 x0 = *(const i32x4*)(src + e);
  i32x4 x1 = *(const i32x4*)(src + e + 4);
  i32x4 x2 = *(const i32x4*)(src + e + 8);
  i32x4 x3 = *(const i32x4*)(src + e + 12);
  i32x4 p;
  p[0] = pack4(x0); p[1] = pack4(x1); p[2] = pack4(x2); p[3] = pack4(x3);
  *(i32x4*)(dst + e) = p;
}

// standalone conv (fallback path)
__global__ void conv_kernel(const int* __restrict__ src, char* __restrict__ dst, long nelem) {
  long t = (long)blockIdx.x * blockDim.x + threadIdx.x;
  long stride = (long)gridDim.x * blockDim.x * 16;
  for (long e = t * 16; e < nelem; e += stride) pack16(src, dst, e);
}

__device__ __forceinline__ void gload_lds16(const void* g, void* l) {
  __builtin_amdgcn_global_load_lds(
      (const __attribute__((address_space(1))) unsigned int*)g,
      (__attribute__((address_space(3))) unsigned int*)l, 16, 0, 0);
}

#define CFENCE() asm volatile("" ::: "memory")

constexpr long A_EL = (long)MPG * KD;   // 8.39M per group
constexpr long B_EL = (long)ND * KD;    // 16.8M per group
constexpr int NTK = KD / 128;           // 32 K-tiles
constexpr int NGEMM_B = 384;            // gemm-role blocks (8*48, swizzlable)
constexpr int NCONV_B = 128;            // conv-role blocks
constexpr int NTILES = GG * 256;        // 2048 tiles of 256x128

// ---------------------------------------------------------------------------
// GEMM tile body (round-7 proven): 256x128 tile, BK=128 B, 4 waves (2Mx2N),
// 48 KiB single-buffer LDS, T2 swizzle, setprio. absmax-verified.
// ---------------------------------------------------------------------------
__device__ __forceinline__ void gemm_tile(
    char* lds, const char* __restrict__ Ag8, const char* __restrict__ Bg8,
    const float* __restrict__ ls, const float* __restrict__ rs,
    float* __restrict__ out, int g, int bm, int bn)
{
  const int tid = threadIdx.x;
  const int lane = tid & 63;
  const int wave = tid >> 6;

  const int srow = tid >> 3;                                  // 0..31
  const int scol = ((tid & 7) << 4) ^ ((srow & 7) << 4);      // involution
  const char* Ag = Ag8 + (size_t)bm * KD;
  const char* Bg = Bg8 + (size_t)bn * KD;
  const int voff = srow * KD + scol;
  char* wbase = lds + wave * 1024;

  auto stage = [&](int kt) {
    const int ko = kt << 7;
#pragma unroll
    for (int i = 0; i < 8; ++i)
      gload_lds16(Ag + (size_t)(ko + voff) + (size_t)i * (32 * KD), wbase + i * 4096);
#pragma unroll
    for (int i = 0; i < 4; ++i)
      gload_lds16(Bg + (size_t)(ko + voff) + (size_t)i * (32 * KD), wbase + 32768 + i * 4096);
  };

  const int wm = wave >> 1;
  const int wn = wave & 1;
  const int r16 = lane & 15;
  const int klane = (lane >> 4) << 4;
  const int sx = (r16 & 7) << 4;
  const char* pA = lds + (size_t)(wm * 128 + r16) * 128;
  const char* pB = lds + 32768 + (size_t)(wn * 64 + r16) * 128;
  const int kx0 = klane ^ sx;
  const int kx1 = (64 + klane) ^ sx;

  i32x4 acc[8][4] = {};

  stage(0);
  asm volatile("s_waitcnt vmcnt(0)" ::: "memory");
  __builtin_amdgcn_s_barrier();
  CFENCE();

#pragma unroll 1
  for (int kt = 0; kt < NTK; ++kt) {
    i32x4 bf0[4], bf1[4], af0[4], af1[4];
#pragma unroll
    for (int n = 0; n < 4; ++n) bf0[n] = *(const i32x4*)(pB + n * 2048 + kx0);
#pragma unroll
    for (int m = 0; m < 4; ++m) af0[m] = *(const i32x4*)(pA + m * 2048 + kx0);
#pragma unroll
    for (int m = 0; m < 4; ++m) af1[m] = *(const i32x4*)(pA + (4 + m) * 2048 + kx0);
    __builtin_amdgcn_s_setprio(1);
#pragma unroll
    for (int m = 0; m < 4; ++m)
#pragma unroll
      for (int n = 0; n < 4; ++n)
        acc[m][n] = __builtin_amdgcn_mfma_i32_16x16x64_i8(af0[m], bf0[n], acc[m][n], 0, 0, 0);
    __builtin_amdgcn_s_setprio(0);
#pragma unroll
    for (int n = 0; n < 4; ++n) bf1[n] = *(const i32x4*)(pB + n * 2048 + kx1);
#pragma unroll
    for (int m = 0; m < 4; ++m) af0[m] = *(const i32x4*)(pA + m * 2048 + kx1);
    __builtin_amdgcn_s_setprio(1);
#pragma unroll
    for (int m = 0; m < 4; ++m)
#pragma unroll
      for (int n = 0; n < 4; ++n)
        acc[4 + m][n] = __builtin_amdgcn_mfma_i32_16x16x64_i8(af1[m], bf0[n], acc[4 + m][n], 0, 0, 0);
    __builtin_amdgcn_s_setprio(0);
#pragma unroll
    for (int m = 0; m < 4; ++m) af1[m] = *(const i32x4*)(pA + (4 + m) * 2048 + kx1);
    __builtin_amdgcn_s_setprio(1);
#pragma unroll
    for (int m = 0; m < 4; ++m)
#pragma unroll
      for (int n = 0; n < 4; ++n)
        acc[m][n] = __builtin_amdgcn_mfma_i32_16x16x64_i8(af0[m], bf1[n], acc[m][n], 0, 0, 0);
#pragma unroll
    for (int m = 0; m < 4; ++m)
#pragma unroll
      for (int n = 0; n < 4; ++n)
        acc[4 + m][n] = __builtin_amdgcn_mfma_i32_16x16x64_i8(af1[m], bf1[n], acc[4 + m][n], 0, 0, 0);
    __builtin_amdgcn_s_setprio(0);

    asm volatile("s_waitcnt lgkmcnt(0)" ::: "memory");
    __builtin_amdgcn_sched_barrier(0);
    __builtin_amdgcn_s_barrier();
    CFENCE();
    if (kt + 1 < NTK) stage(kt + 1);
    asm volatile("s_waitcnt vmcnt(0)" ::: "memory");
    __builtin_amdgcn_s_barrier();
    CFENCE();
  }

  const size_t orow0 = (size_t)g * MPG + bm + wm * 128 + ((lane >> 4) << 2);
  const int col0 = bn + wn * 64 + r16;
  float rsv[4];
#pragma unroll
  for (int n = 0; n < 4; ++n) rsv[n] = rs[(size_t)g * ND + col0 + n * 16];
#pragma unroll
  for (int m = 0; m < 8; ++m) {
#pragma unroll
    for (int q = 0; q < 4; ++q) {
      size_t row = orow0 + m * 16 + q;
      float lsv = ls[row];
#pragma unroll
      for (int n = 0; n < 4; ++n)
        out[row * ND + col0 + n * 16] = (float)acc[m][n][q] * lsv * rsv[n];
    }
  }
}

// ---------------------------------------------------------------------------
// Cooperative producer/consumer kernel. All 512 blocks co-resident (2/CU).
//   blocks [0,384):   GEMM role — grid-stride over 2048 group-ordered tiles,
//                     spin (capped) on flags[0] >= group+1.
//   blocks [384,512): conv role — convert groups 0..7 in order; after each,
//                     release-publish via done-counter -> ready-counter.
// flags: [0]=ready groups, [1..8]=per-group done block count. Zeroed per call.
// ---------------------------------------------------------------------------
__global__ __launch_bounds__(256, 2) void mega_i8(
    const int* __restrict__ A32, const int* __restrict__ B32,
    char* __restrict__ wsA, char* __restrict__ wsB,
    const float* __restrict__ ls, const float* __restrict__ rs,
    float* __restrict__ out, int* __restrict__ flags)
{
  extern __shared__ char lds[];   // 49152 B (gemm role only)
  const int tid = threadIdx.x;

  if (blockIdx.x >= NGEMM_B) {
    // ---------------- conv role ----------------
    const int cb = blockIdx.x - NGEMM_B;
    const long nthr = (long)NCONV_B * 256;
    const long t0 = (long)cb * 256 + tid;
    for (int g = 0; g < GG; ++g) {
      {
        const int* src = A32 + (size_t)g * A_EL;
        char* dst = wsA + (size_t)g * A_EL;
        for (long e = t0 * 64; e < A_EL; e += nthr * 64) {
          pack16(src, dst, e);      pack16(src, dst, e + 16);
          pack16(src, dst, e + 32); pack16(src, dst, e + 48);
        }
      }
      {
        const int* src = B32 + (size_t)g * B_EL;
        char* dst = wsB + (size_t)g * B_EL;
        for (long e = t0 * 64; e < B_EL; e += nthr * 64) {
          pack16(src, dst, e);      pack16(src, dst, e + 16);
          pack16(src, dst, e + 32); pack16(src, dst, e + 48);
        }
      }
      __threadfence();        // release: group-g stores visible device-wide
      __syncthreads();
      if (tid == 0) {
        if (atomicAdd(&flags[1 + g], 1) == NCONV_B - 1)
          atomicAdd(&flags[0], 1);   // group g fully converted
      }
    }
    return;
  }

  // ---------------- gemm role ----------------
  const int b = blockIdx.x;
  const int bs = (b & 7) * (NGEMM_B / 8) + (b >> 3);   // XCD-chunk swizzle
#pragma unroll 1
  for (int t = bs; t < NTILES; t += NGEMM_B) {
    const int grp = t >> 8;
    const int idx = t & 255;
    const int bm = (idx >> 5) * 256;
    const int bn = (idx & 31) * 128;
    if (tid == 0) {
      int cap = 0;
      while (atomicAdd(&flags[0], 0) < grp + 1) {
        __builtin_amdgcn_s_sleep(2);
        if (++cap > 5000000) break;   // safety: terminate rather than hang
      }
    }
    __syncthreads();
    __threadfence();        // acquire before reading freshly-converted ws
    gemm_tile(lds, wsA + (size_t)grp * A_EL, wsB + (size_t)grp * B_EL,
              ls, rs, out, grp, bm, bn);
  }
}

// ---------------------------------------------------------------------------
// Fallback GEMM (round-4, best proven serial): 256x256 tile, 8 waves,
// 128 KiB LDS dbuf, 4-phase interleave. GEMM 316 us, absmax 4.0.
// ---------------------------------------------------------------------------
__global__ __launch_bounds__(512, 2) void gemm256sq_i8(
    const char* __restrict__ Aall, const char* __restrict__ Ball,
    const float* __restrict__ ls, const float* __restrict__ rs,
    float* __restrict__ out, int g0, int nwg)
{
  extern __shared__ char lds[];   // 131072 B
  const int tid = threadIdx.x;
  const int lane = tid & 63;
  const int wave = tid >> 6;

  int bid = blockIdx.x;
  int wg = (bid & 7) * (nwg >> 3) + (bid >> 3);
  const int gl = wg >> 7;
  const int rr_ = wg & 127;
  const int bm = (rr_ >> 4) * 256;
  const int bn = (rr_ & 15) * 256;
  const int g = g0 + gl;

  const int srow = tid >> 3;
  const int scol = ((tid & 7) << 4) ^ ((srow & 7) << 4);
  const char* Ag = Aall + ((size_t)gl * MPG + bm) * KD;
  const char* Bg = Ball + ((size_t)gl * ND + bn) * KD;
  const char* pa[4]; const char* pb[4];
#pragma unroll
  for (int i = 0; i < 4; ++i) {
    pa[i] = Ag + (size_t)(i * 64 + srow) * KD + scol;
    pb[i] = Bg + (size_t)(i * 64 + srow) * KD + scol;
  }
  char* wbase = lds + wave * 1024;

  auto stageA = [&](int buf, int kt) {
    const int ko = kt << 7;
    char* d = wbase + buf * 65536;
#pragma unroll
    for (int i = 0; i < 4; ++i) gload_lds16(pa[i] + ko, d + i * 8192);
  };
  auto stageB = [&](int buf, int kt) {
    const int ko = kt << 7;
    char* d = wbase + buf * 65536 + 32768;
#pragma unroll
    for (int i = 0; i < 4; ++i) gload_lds16(pb[i] + ko, d + i * 8192);
  };

  const int wm = wave >> 2;
  const int wn = wave & 3;
  const int r16 = lane & 15;
  const int klane = (lane >> 4) << 4;
  const int sx = (r16 & 7) << 4;
  const char* aBase0 = lds + (size_t)(wm * 128 + r16) * 128;
  const char* bBase0 = lds + 32768 + (size_t)(wn * 64 + r16) * 128;

  i32x4 acc[8][4] = {};

  stageA(0, 0); stageB(0, 0);
  asm volatile("s_waitcnt vmcnt(0)" ::: "memory");
  __builtin_amdgcn_s_barrier();
  CFENCE();

#pragma unroll 1
  for (int kt = 0; kt < NTK; ++kt) {
    const int c = kt & 1;
    const char* pA = aBase0 + c * 65536;
    const char* pB = bBase0 + c * 65536;
    const int kx0 = klane ^ sx;
    const int kx1 = (64 + klane) ^ sx;
    const bool pre = (kt + 1 < NTK);
    i32x4 af[4], bf[4];

#pragma unroll
    for (int n = 0; n < 4; ++n) bf[n] = *(const i32x4*)(pB + n * 2048 + kx0);
#pragma unroll
    for (int m = 0; m < 4; ++m) af[m] = *(const i32x4*)(pA + m * 2048 + kx0);
    if (pre) stageA(c ^ 1, kt + 1);
    CFENCE(); __builtin_amdgcn_s_barrier(); CFENCE();
    __builtin_amdgcn_s_setprio(1);
#pragma unroll
    for (int m = 0; m < 4; ++m)
#pragma unroll
      for (int n = 0; n < 4; ++n)
        acc[m][n] = __builtin_amdgcn_mfma_i32_16x16x64_i8(af[m], bf[n], acc[m][n], 0, 0, 0);
    __builtin_amdgcn_s_setprio(0);
    CFENCE(); __builtin_amdgcn_s_barrier(); CFENCE();

#pragma unroll
    for (int m = 0; m < 4; ++m) af[m] = *(const i32x4*)(pA + (4 + m) * 2048 + kx0);
    if (pre) stageB(c ^ 1, kt + 1);
    CFENCE(); __builtin_amdgcn_s_barrier(); CFENCE();
    __builtin_amdgcn_s_setprio(1);
#pragma unroll
    for (int m = 0; m < 4; ++m)
#pragma unroll
      for (int n = 0; n < 4; ++n)
        acc[4 + m][n] = __builtin_amdgcn_mfma_i32_16x16x64_i8(af[m], bf[n], acc[4 + m][n], 0, 0, 0);
    __builtin_amdgcn_s_setprio(0);
    CFENCE(); __builtin_amdgcn_s_barrier(); CFENCE();

#pragma unroll
    for (int n = 0; n < 4; ++n) bf[n] = *(const i32x4*)(pB + n * 2048 + kx1);
#pragma unroll
    for (int m = 0; m < 4; ++m) af[m] = *(const i32x4*)(pA + m * 2048 + kx1);
    CFENCE(); __builtin_amdgcn_s_barrier(); CFENCE();
    __builtin_amdgcn_s_setprio(1);
#pragma unroll
    for (int m = 0; m < 4; ++m)
#pragma unroll
      for (int n = 0; n < 4; ++n)
        acc[m][n] = __builtin_amdgcn_mfma_i32_16x16x64_i8(af[m], bf[n], acc[m][n], 0, 0, 0);
    __builtin_amdgcn_s_setprio(0);
    CFENCE(); __builtin_amdgcn_s_barrier(); CFENCE();

#pragma unroll
    for (int m = 0; m < 4; ++m) af[m] = *(const i32x4*)(pA + (4 + m) * 2048 + kx1);
    asm volatile("s_waitcnt vmcnt(0)" ::: "memory");
    CFENCE(); __builtin_amdgcn_s_barrier(); CFENCE();
    __builtin_amdgcn_s_setprio(1);
#pragma unroll
    for (int m = 0; m < 4; ++m)
#pragma unroll
      for (int n = 0; n < 4; ++n)
        acc[4 + m][n] = __builtin_amdgcn_mfma_i32_16x16x64_i8(af[m], bf[n], acc[4 + m][n], 0, 0, 0);
    __builtin_amdgcn_s_setprio(0);
    CFENCE(); __builtin_amdgcn_s_barrier(); CFENCE();
  }

  const size_t orow0 = (size_t)g * MPG + bm + wm * 128 + ((lane >> 4) << 2);
  const int col0 = bn + wn * 64 + r16;
  float rsv[4];
#pragma unroll
  for (int n = 0; n < 4; ++n) rsv[n] = rs[(size_t)g * ND + col0 + n * 16];
#pragma unroll
  for (int m = 0; m < 8; ++m) {
#pragma unroll
    for (int q = 0; q < 4; ++q) {
      size_t row = orow0 + m * 16 + q;
      float lsv = ls[row];
#pragma unroll
      for (int n = 0; n < 4; ++n)
        out[row * ND + col0 + n * 16] = (float)acc[m][n][q] * lsv * rsv[n];
    }
  }
}

extern "C" void kernel_launch(void* const* d_in, const int* in_sizes, int n_in,
                              void* d_out, int out_size, void* d_ws, size_t ws_size,
                              hipStream_t stream) {
  const int* A32 = (const int*)d_in[0];
  const int* B32 = (const int*)d_in[1];
  const float* ls = (const float*)d_in[2];
  const float* rs = (const float*)d_in[3];
  float* out = (float*)d_out;

  const size_t aE = (size_t)GG * A_EL;
  const size_t bE = (size_t)GG * B_EL;

  // ---------- try the cooperative producer/consumer path ----------
  if (d_ws && ws_size >= aE + bE + 64) {
    int dev = 0;
    hipGetDevice(&dev);
    int coop = 0;
    hipDeviceGetAttribute(&coop, hipDeviceAttributeCooperativeLaunch, dev);
    if (coop) {
      if (hipFuncSetAttribute((const void*)mega_i8,
                              hipFuncAttributeMaxDynamicSharedMemorySize,
                              49152) == hipSuccess) {
        int nb = 0;
        hipOccupancyMaxActiveBlocksPerMultiprocessor(&nb, (const void*)mega_i8, 256, 49152);
        hipDeviceProp_t prop;
        hipGetDeviceProperties(&prop, dev);
        if ((long)nb * prop.multiProcessorCount >= NGEMM_B + NCONV_B) {
          char* wsA = (char*)d_ws;
          char* wsB = wsA + aE;
          int* flags = (int*)(wsA + aE + bE);
          hipMemsetAsync(flags, 0, 64, stream);
          const int* a32 = A32; const int* b32 = B32;
          const float* lsp = ls; const float* rsp = rs;
          float* outp = out;
          void* args[] = {(void*)&a32, (void*)&b32, (void*)&wsA, (void*)&wsB,
                          (void*)&lsp, (void*)&rsp, (void*)&outp, (void*)&flags};
          hipError_t e = hipLaunchCooperativeKernel(
              (const void*)mega_i8, dim3(NGEMM_B + NCONV_B), dim3(256),
              args, 49152, stream);
          if (e == hipSuccess) return;
        }
      }
    }
  }

  // ---------- fallback: proven serial conv + round-4 GEMM (484 us) ----------
  if (d_ws && ws_size >= aE + bE) {
    char* wsA = (char*)d_ws;
    char* wsB = wsA + aE;
    conv_kernel<<<8192, 256, 0, stream>>>(A32, wsA, (long)aE);
    conv_kernel<<<16384, 256, 0, stream>>>(B32, wsB, (long)bE);
    if (hipFuncSetAttribute((const void*)gemm256sq_i8,
                            hipFuncAttributeMaxDynamicSharedMemorySize,
                            131072) == hipSuccess) {
      gemm256sq_i8<<<1024, 512, 131072, stream>>>(wsA, wsB, ls, rs, out, 0, 1024);
      return;
    }
  }

  // last resort: per-group conv + round-4 GEMM slices (needs only slab ws)
  if (d_ws && ws_size >= (size_t)(A_EL + B_EL)) {
    char* wsA = (char*)d_ws;
    char* wsB = wsA + A_EL;
    hipFuncSetAttribute((const void*)gemm256sq_i8,
                        hipFuncAttributeMaxDynamicSharedMemorySize, 131072);
    for (int g = 0; g < GG; ++g) {
      conv_kernel<<<2048, 256, 0, stream>>>(A32 + (size_t)g * A_EL, wsA, (long)A_EL);
      conv_kernel<<<4096, 256, 0, stream>>>(B32 + (size_t)g * B_EL, wsB, (long)B_EL);
      gemm256sq_i8<<<128, 512, 131072, stream>>>(wsA, wsB, ls, rs, out, g, 128);
    }
  }
}